// Round 11
// baseline (211.036 us; speedup 1.0000x reference)
//
#include <hip/hip_runtime.h>
#include <hip/hip_bf16.h>
#include <math.h>

// B=2, L=2048, D=1024, H=16, HD=64
#define NB_L 2048
#define GM 4096          // B*L rows
#define GN 3072          // 3*D cols
#define GK 1024
#define NROWS 65536      // B*H*L partial rows per split
#define SCALE_L2E 0.180336880f   // 0.125 * log2(e), folded into Q at GEMM epilogue

typedef float  f4v __attribute__((ext_vector_type(4)));
typedef short  s4v __attribute__((ext_vector_type(4)));
typedef short  s8v __attribute__((ext_vector_type(8)));

#define MFMA_16x16x32(a, b, c) __builtin_amdgcn_mfma_f32_16x16x32_bf16((a), (b), (c), 0, 0, 0)
#define MFMA_16x16x16(a, b, c) __builtin_amdgcn_mfma_f32_16x16x16bf16_1k((a), (b), (c), 0, 0, 0)

static __device__ __forceinline__ unsigned int bfpk(float a, float b) {
    __hip_bfloat162 h = __float22bfloat162_rn(float2{a, b});
    union { __hip_bfloat162 h2; unsigned int u; } cv; cv.h2 = h; return cv.u;
}
// Fast f32x2 -> packed bf16x2 (round-half-up via +0x8000, then byte-perm).
static __device__ __forceinline__ unsigned int pkrnd(float a, float b) {
    union { float f; unsigned int u; } ua, ub;
    ua.f = a; ub.f = b;
    return __builtin_amdgcn_perm(ub.u + 0x8000u, ua.u + 0x8000u, 0x07060302u);
}
static __device__ __forceinline__ unsigned short bf1(float a) {
    union { __hip_bfloat16 h; unsigned short u; } cv; cv.h = __float2bfloat16(a); return cv.u;
}
static __device__ __forceinline__ float bf2f(unsigned short u) {
    union { unsigned int u; float f; } cv; cv.u = ((unsigned int)u) << 16; return cv.f;
}

// async global->LDS, 16B per lane
static __device__ __forceinline__ void gl_lds16(const ushort* g, ushort* l) {
    __builtin_amdgcn_global_load_lds((const __attribute__((address_space(1))) void*)g,
                                     (__attribute__((address_space(3))) void*)l, 16, 0, 0);
}

// ---------------------------------------------------------------------------
// Fused input prep: blocks [0,2048) convert X f32->bf16; blocks [2048,2816)
// convert+transpose W -> Wt [3072,1024] bf16 (k contiguous).
// ---------------------------------------------------------------------------
__global__ __launch_bounds__(256) void conv_fused(
    const float* __restrict__ X, const float* __restrict__ W,
    ushort* __restrict__ Xb, ushort* __restrict__ Wt)
{
    __shared__ __align__(16) ushort T[64][72];
    const int bid = blockIdx.x, t = threadIdx.x;
    if (bid < 2048) {
        const int i = bid * 256 + t;
        const float4 f0 = ((const float4*)X)[2 * i];
        const float4 f1 = ((const float4*)X)[2 * i + 1];
        uint4 u;
        u.x = bfpk(f0.x, f0.y); u.y = bfpk(f0.z, f0.w);
        u.z = bfpk(f1.x, f1.y); u.w = bfpk(f1.z, f1.w);
        ((uint4*)Xb)[i] = u;
    } else {
        const int wb = bid - 2048;                 // 0..767
        const int k0 = (wb & 15) * 64, n0 = (wb >> 4) * 64;
        {
            const int kr = t >> 2, nc0 = (t & 3) * 16;
            const float* src = W + (size_t)(k0 + kr) * GN + n0 + nc0;
#pragma unroll
            for (int u = 0; u < 4; ++u) {
                const float4 v = *(const float4*)(src + 4 * u);
                T[nc0 + 4 * u + 0][kr] = bf1(v.x);
                T[nc0 + 4 * u + 1][kr] = bf1(v.y);
                T[nc0 + 4 * u + 2][kr] = bf1(v.z);
                T[nc0 + 4 * u + 3][kr] = bf1(v.w);
            }
        }
        __syncthreads();
        {
            const int nr = t >> 2, kc0 = (t & 3) * 16;
            ushort* dst = Wt + (size_t)(n0 + nr) * GK + k0 + kc0;
            *(s8v*)dst       = *(const s8v*)&T[nr][kc0];
            *(s8v*)(dst + 8) = *(const s8v*)&T[nr][kc0 + 8];
        }
    }
}

// ---------------------------------------------------------------------------
// bf16 MFMA GEMM — round-3 4-phase version, BYTE-IDENTICAL to r10 (serves as
// a replication probe for r10's anomalous 69 us reading on identical source;
// r3/r9 profiles bounded it <49.4 us.  VGPR changed 104->96 with no source
// change = co-compile perturbation suspect).
// BM=128 x BN=384, BK=64, 512 thr (8 waves, 2M x 4N), 128 KiB LDS,
// grid 32x8 = 256 blocks = exactly 1/CU; chunk-XOR swizzle (0 conflicts).
// ---------------------------------------------------------------------------
__global__ __launch_bounds__(512, 2) void qkv_gemm_bf16(
    const ushort* __restrict__ Xb, const ushort* __restrict__ Wt,
    ushort* __restrict__ Qh, ushort* __restrict__ Kh, ushort* __restrict__ VT)
{
    __shared__ __align__(16) ushort As[2][2][128][32];   // 32 KB [buf][khalf][row][k]
    __shared__ __align__(16) ushort Bs[2][2][384][32];   // 96 KB

    const int tid = threadIdx.x;
    const int bid = blockIdx.x;

    // XCD region swizzle: tile grid 32(y) x 8(x); xcd owns 8y x 4x region
    const int xcd = bid & 7, idx = bid >> 3;             // idx in [0,32)
    const int ytile = ((xcd >> 1) << 3) + (idx & 7);     // 0..31
    const int xtile = ((xcd & 1) << 2) + (idx >> 3);     // 0..7
    const int row0 = ytile << 7;                         // *128
    const int col0 = xtile * 384;

    const int lane = tid & 63, w = tid >> 6;
    const int wm = w >> 2, wn = w & 3;                   // 2M x 4N wave grid
    const int lq = lane & 15, quad = lane >> 4;

    // staging decomposition: thread -> (row-within-issue rS, physical chunk pA)
    const int rS = tid >> 2, pA = tid & 3;               // rS in [0,128)
    const int cA = pA ^ ((rS >> 1) & 3);                 // logical chunk (inverse swizzle)
    const ushort* gA0 = Xb + (size_t)(row0 + rS) * GK + cA * 8;
    const ushort* gB0 = Wt + (size_t)(col0 + rS) * GK + cA * 8;

    // frag-read physical chunk (element offset within 32-k row)
    const int pq = (quad ^ ((lq >> 1) & 3)) * 8;
    const int rowA = wm * 64 + lq;
    const int rowB = wn * 96 + lq;

    f4v acc[4][6];
#pragma unroll
    for (int mf = 0; mf < 4; ++mf)
#pragma unroll
        for (int nf = 0; nf < 6; ++nf) acc[mf][nf] = 0.f;

    auto stA = [&](int t, int h) {
        gl_lds16(gA0 + t * 64 + h * 32, &As[t & 1][h][rS][pA * 8]);
    };
    auto stB = [&](int t, int h, int u) {
        gl_lds16(gB0 + (size_t)u * 128 * GK + t * 64 + h * 32,
                 &Bs[t & 1][h][u * 128 + rS][pA * 8]);
    };

    // prologue: t0 fully + t1 kh0 last; newest 4 (t1 kh0 group) stay in flight
    stA(0, 0);
    stB(0, 0, 0); stB(0, 0, 1); stB(0, 0, 2);
    stA(0, 1);
    stB(0, 1, 0); stB(0, 1, 1); stB(0, 1, 2);
    stA(1, 0);
    stB(1, 0, 0); stB(1, 0, 1); stB(1, 0, 2);
    asm volatile("s_waitcnt vmcnt(4)" ::: "memory");
    __builtin_amdgcn_s_barrier();
    asm volatile("" ::: "memory");

    const int NT = GK / 64;   // 16
#pragma unroll 2
    for (int t = 0; t < NT; ++t) {
        const int cur = t & 1;
        s8v af[4], bfr[3];

        // ---- phase 0: kh0, N-lo ----
#pragma unroll
        for (int nf = 0; nf < 3; ++nf) bfr[nf] = *(const s8v*)&Bs[cur][0][rowB + nf * 16][pq];
#pragma unroll
        for (int mf = 0; mf < 4; ++mf) af[mf] = *(const s8v*)&As[cur][0][rowA + mf * 16][pq];
        if (t + 1 < NT) { stB(t + 1, 1, 0); stB(t + 1, 1, 1); stB(t + 1, 1, 2); }
        __builtin_amdgcn_s_barrier();
        asm volatile("s_waitcnt lgkmcnt(0)");
        __builtin_amdgcn_s_setprio(1);
#pragma unroll
        for (int mf = 0; mf < 4; ++mf)
#pragma unroll
            for (int nf = 0; nf < 3; ++nf)
                acc[mf][nf] = MFMA_16x16x32(af[mf], bfr[nf], acc[mf][nf]);
        __builtin_amdgcn_s_setprio(0);
        __builtin_amdgcn_s_barrier();

        // ---- phase 1: kh0, N-hi (A frags reused) ----
#pragma unroll
        for (int nf = 0; nf < 3; ++nf) bfr[nf] = *(const s8v*)&Bs[cur][0][rowB + 48 + nf * 16][pq];
        if (t + 1 < NT) stA(t + 1, 1);
        __builtin_amdgcn_s_barrier();
        asm volatile("s_waitcnt lgkmcnt(0)");
        __builtin_amdgcn_s_setprio(1);
#pragma unroll
        for (int mf = 0; mf < 4; ++mf)
#pragma unroll
            for (int nf = 0; nf < 3; ++nf)
                acc[mf][nf + 3] = MFMA_16x16x32(af[mf], bfr[nf], acc[mf][nf + 3]);
        __builtin_amdgcn_s_setprio(0);
        __builtin_amdgcn_s_barrier();

        // ---- phase 2: kh1, N-lo ----
#pragma unroll
        for (int nf = 0; nf < 3; ++nf) bfr[nf] = *(const s8v*)&Bs[cur][1][rowB + nf * 16][pq];
#pragma unroll
        for (int mf = 0; mf < 4; ++mf) af[mf] = *(const s8v*)&As[cur][1][rowA + mf * 16][pq];
        if (t + 2 < NT) stA(t + 2, 0);   // cur-buf kh0: last read was ph0
        __builtin_amdgcn_s_barrier();
        asm volatile("s_waitcnt lgkmcnt(0)");
        __builtin_amdgcn_s_setprio(1);
#pragma unroll
        for (int mf = 0; mf < 4; ++mf)
#pragma unroll
            for (int nf = 0; nf < 3; ++nf)
                acc[mf][nf] = MFMA_16x16x32(af[mf], bfr[nf], acc[mf][nf]);
        __builtin_amdgcn_s_setprio(0);
        __builtin_amdgcn_s_barrier();

        // ---- phase 3: kh1, N-hi ----
#pragma unroll
        for (int nf = 0; nf < 3; ++nf) bfr[nf] = *(const s8v*)&Bs[cur][1][rowB + 48 + nf * 16][pq];
        if (t + 2 < NT) { stB(t + 2, 0, 0); stB(t + 2, 0, 1); stB(t + 2, 0, 2); }
        __builtin_amdgcn_s_barrier();
        asm volatile("s_waitcnt lgkmcnt(0)");
        __builtin_amdgcn_s_setprio(1);
#pragma unroll
        for (int mf = 0; mf < 4; ++mf)
#pragma unroll
            for (int nf = 0; nf < 3; ++nf)
                acc[mf][nf + 3] = MFMA_16x16x32(af[mf], bfr[nf], acc[mf][nf + 3]);
        __builtin_amdgcn_s_setprio(0);
        // keep the newest 4 (t+2 kh0 group) in flight; drain only in tail
        if (t + 2 < NT) asm volatile("s_waitcnt vmcnt(4)" ::: "memory");
        else            asm volatile("s_waitcnt vmcnt(0)" ::: "memory");
        __builtin_amdgcn_s_barrier();
        asm volatile("" ::: "memory");
    }

    // epilogue: row = row0 + wm*64 + mf*16 + quad*4 + r
    //           col = col0 + wn*96 + nf*16 + lq
#pragma unroll
    for (int mf = 0; mf < 4; ++mf)
#pragma unroll
        for (int nf = 0; nf < 6; ++nf) {
            const int colg = col0 + wn * 96 + nf * 16 + lq;
            const int part = colg >> 10;          // uniform per nf-frag (16 | 1024)
            const int colp = colg & 1023;
            const int hh = colp >> 6, d = colp & 63;
#pragma unroll
            for (int r = 0; r < 4; ++r) {
                const int row = row0 + wm * 64 + mf * 16 + quad * 4 + r;
                const int b = row >> 11, tok = row & 2047;
                const int bh = b * 16 + hh;
                if (part == 0) {
                    Qh[((size_t)bh * 2048 + tok) * 64 + d] = bf1(acc[mf][nf][r] * SCALE_L2E);
                } else if (part == 1) {
                    Kh[((size_t)bh * 2048 + tok) * 64 + (d ^ ((tok & 7) << 3))] = bf1(acc[mf][nf][r]);
                } else {
                    VT[((size_t)bh * 64 + d) * 2048 + (tok ^ ((d & 7) << 3))] = bf1(acc[mf][nf][r]);
                }
            }
        }
}

// ---------------------------------------------------------------------------
// Flash attention — round-11: K-SPLIT=4 for full occupancy.
//
// r10 (K-split=2, 512 blk x 8 waves = 16 waves/CU) improved total by 8 us,
// confirming wave count is attn's binding constraint.  Grid was the cap:
// split K into quarters -> 1024 blocks x 512 thr = 4 blocks/CU x 8 waves =
// 32 waves/CU (full).  LDS 4x32KB=128K <= 160K; launch_bounds(512,8) pins
// VGPR <= 64 (8 waves/SIMD).
//
// Work: (bh, qt, s): kt in [s*T/4, (s+1)*T/4), T = 2qt+2.  Pieces {qp,15-qp}
// -> per-block iters 8-9 (near-uniform).  niter may be 0 (writes zeros).
//
// Partial storage (ws dead region is 23.1 MB; 4 bf16 partials = 33.6 MB):
//   s=0,1 -> Opart (bf16) + Lp[0..1] in ws  (16.8 + 0.5 MB)
//   s=2,3 -> PACKED INTO Out's f32 slots: each f32 slot's {low,high} ushort
//            = bf16 partial {s2,s3} for that (row,d).  Byte-disjoint stores,
//            no race; combine reads its own slot before overwriting it.
//   Lp[2..3] in ws (0.5 MB).  No dependence on Out's initial contents.
// ---------------------------------------------------------------------------
__global__ __launch_bounds__(512, 8) void attn_bf16(
    const ushort* __restrict__ Qh, const ushort* __restrict__ Kh,
    const ushort* __restrict__ VT, ushort* __restrict__ Opart,
    float* __restrict__ Lp, float* __restrict__ OutS)
{
    __shared__ __align__(16) ushort Ks[2][64 * 64];   // [krow][d^swz]
    __shared__ __align__(16) ushort Vt[2][64 * 64];   // [d][k^swz]

    const int x = blockIdx.x;            // 1024 blocks
    const int bh = x & 31;               // same-bh blocks share an XCD (x%8==bh%8)
    const int y = x >> 5;                // [0,32)
    const int s = y & 3;                 // K-quarter
    const int qp = y >> 2;               // [0,8)

    const int tid = threadIdx.x;
    const int w = tid >> 6, lane = tid & 63;   // w in [0,8)
    const int lq = lane & 15, quad = lane >> 4;
    const int kswz = (lq & 7) << 3;

    const ushort* kbase = Kh + (size_t)bh * 2048 * 64;
    const ushort* vbase = VT + (size_t)bh * 64 * 2048;
    // staging: 512 thr x 16B = 8 KB = one full 64x64 bf16 tile per issue
    const int kr = tid >> 3, ko = (tid & 7) * 8;      // kr in [0,64)

    auto stage = [&](int kt, int bufi) {
        gl_lds16(kbase + (size_t)kt * 64 * 64 + kr * 64 + ko, &Ks[bufi][tid * 8]);
        gl_lds16(vbase + (size_t)kr * 2048 + kt * 64 + ko,    &Vt[bufi][tid * 8]);
    };

    const s4v ones = { (short)0x3F80, (short)0x3F80, (short)0x3F80, (short)0x3F80 };

#pragma unroll 1
    for (int piece = 0; piece < 2; ++piece) {
        const int qt = piece ? (15 - qp) : qp;
        const int qrow_base = qt * 128 + w * 16;      // 8 waves x 16 rows
        const int diag = 2 * qt + (w >> 2);           // wave's diagonal K-tile
        const int T = 2 * qt + 2;                     // total K-tiles for qt
        const int kt_lo = (s * T) >> 2;
        const int kt_hi = ((s + 1) * T) >> 2;
        const int niter = kt_hi - kt_lo;              // may be 0

        // piece 2: ensure all waves finished piece-1 reads before buf0 reuse
        if (piece) __builtin_amdgcn_s_barrier();

        s8v qf[2];
#pragma unroll
        for (int sb = 0; sb < 2; ++sb)
            qf[sb] = *(const s8v*)(Qh + ((size_t)bh * 2048 + qrow_base + lq) * 64
                                   + sb * 32 + quad * 8);

        f4v o[4];
#pragma unroll
        for (int dg = 0; dg < 4; ++dg) o[dg] = 0.f;
        f4v lacc = 0.f;

        auto compute = [&](int ktc, int bufi) {
            if (ktc > diag) return;
            f4v st[4];
#pragma unroll
            for (int kg = 0; kg < 4; ++kg) st[kg] = 0.f;
#pragma unroll
            for (int kg = 0; kg < 4; ++kg)
#pragma unroll
                for (int sb = 0; sb < 2; ++sb) {
                    const s8v af = *(const s8v*)&Ks[bufi][(kg * 16 + lq) * 64
                                                         + ((sb * 32 + quad * 8) ^ kswz)];
                    st[kg] = MFMA_16x16x32(af, qf[sb], st[kg]);
                }
            if (ktc == diag) {
                const int qrow = qrow_base + lq;
#pragma unroll
                for (int kg = 0; kg < 4; ++kg)
#pragma unroll
                    for (int r = 0; r < 4; ++r)
                        if (ktc * 64 + kg * 16 + quad * 4 + r > qrow)
                            st[kg][r] = -INFINITY;
            }
#pragma unroll
            for (int kg = 0; kg < 4; ++kg)
#pragma unroll
                for (int r = 0; r < 4; ++r)
                    st[kg][r] = exp2f(st[kg][r]);
#pragma unroll
            for (int ks = 0; ks < 4; ++ks) {
                s4v pb;
                {
                    union { s4v v; uint2 u; } c;
                    c.u.x = pkrnd(st[ks][0], st[ks][1]);
                    c.u.y = pkrnd(st[ks][2], st[ks][3]);
                    pb = c.v;
                }
                lacc = MFMA_16x16x16(ones, pb, lacc);
#pragma unroll
                for (int dg = 0; dg < 4; ++dg) {
                    const s4v va = *(const s4v*)&Vt[bufi][(dg * 16 + lq) * 64
                                                         + ((ks * 16 + quad * 4) ^ kswz)];
                    o[dg] = MFMA_16x16x16(va, pb, o[dg]);
                }
            }
        };

        if (niter > 0) {
            stage(kt_lo, 0);                           // 2 loads in flight
#pragma unroll 1
            for (int i = 0; i < niter; ++i) {
                const int cur = i & 1;
                __builtin_amdgcn_s_barrier();          // B1: all compute(i-1) done
                if (i + 1 < niter) {
                    stage(kt_lo + i + 1, cur ^ 1);     // +2 -> 4 outstanding
                    asm volatile("s_waitcnt vmcnt(2)" ::: "memory");   // retire buf-i's 2
                } else {
                    asm volatile("s_waitcnt vmcnt(0)" ::: "memory");   // piece tail drain
                }
                __builtin_amdgcn_s_barrier();          // B2: everyone's buf-i landed
                compute(kt_lo + i, cur);
            }
        }

        // piece epilogue: wave writes its 16 rows for this split
        {
            const int qrow = qrow_base + lq;
            const size_t prow = (size_t)(s * 32 + bh) * 2048 + qrow;   // = s*NROWS + row
            if (s < 2) {
#pragma unroll
                for (int dg = 0; dg < 4; ++dg) {
                    const int d = dg * 16 + quad * 4;
                    uint2 u;
                    u.x = bfpk(o[dg][0], o[dg][1]);
                    u.y = bfpk(o[dg][2], o[dg][3]);
                    *(uint2*)&Opart[prow * 64 + d] = u;
                }
            } else {
                // pack into Out f32 slots: low ushort = s2, high ushort = s3
                const int b_ = bh >> 4, h = bh & 15;
                const size_t fbase = ((size_t)(b_ * 2048 + qrow)) * 1024 + h * 64;
                ushort* op = (ushort*)OutS;
                const int hilo = s & 1;
#pragma unroll
                for (int dg = 0; dg < 4; ++dg) {
                    const int d = dg * 16 + quad * 4;
#pragma unroll
                    for (int r = 0; r < 4; ++r)
                        op[2 * (fbase + d + r) + hilo] = bf1(o[dg][r]);
                }
            }
            if (quad == 0) Lp[prow] = lacc[0];
        }
    }
}

// ---------------------------------------------------------------------------
// Combine the four K-split partials -> final f32 output [B, L, D].
// s0,s1 from Opart/ws; s2,s3 read from Out's own slots (then overwritten).
// ---------------------------------------------------------------------------
__global__ __launch_bounds__(256) void attn_combine(
    const ushort* __restrict__ Opart, const float* __restrict__ Lp, float* __restrict__ Out)
{
    const int id = blockIdx.x * 256 + threadIdx.x;
    const int row = id >> 4, c4 = (id & 15) * 4;
    const float l = Lp[row] + Lp[row + NROWS] + Lp[row + 2 * NROWS] + Lp[row + 3 * NROWS];
    const float inv = 1.0f / l;

    const s4v a = *(const s4v*)&Opart[(size_t)row * 64 + c4];
    const s4v c = *(const s4v*)&Opart[(size_t)(row + NROWS) * 64 + c4];

    const int bh = row >> 11, qrow = row & 2047;
    const int b = bh >> 4, h = bh & 15;
    float* outp = Out + ((size_t)(b * 2048 + qrow)) * 1024 + h * 64 + c4;
    const uint4 slot = *(const uint4*)outp;   // packed {s2,s3} bf16 halves

    float4 v;
    v.x = (bf2f((unsigned short)a[0]) + bf2f((unsigned short)c[0])
         + bf2f((unsigned short)(slot.x & 0xffff)) + bf2f((unsigned short)(slot.x >> 16))) * inv;
    v.y = (bf2f((unsigned short)a[1]) + bf2f((unsigned short)c[1])
         + bf2f((unsigned short)(slot.y & 0xffff)) + bf2f((unsigned short)(slot.y >> 16))) * inv;
    v.z = (bf2f((unsigned short)a[2]) + bf2f((unsigned short)c[2])
         + bf2f((unsigned short)(slot.z & 0xffff)) + bf2f((unsigned short)(slot.z >> 16))) * inv;
    v.w = (bf2f((unsigned short)a[3]) + bf2f((unsigned short)c[3])
         + bf2f((unsigned short)(slot.w & 0xffff)) + bf2f((unsigned short)(slot.w >> 16))) * inv;

    *(float4*)outp = v;
}

// ---------------------------------------------------------------------------
extern "C" void kernel_launch(void* const* d_in, const int* in_sizes, int n_in,
                              void* d_out, int out_size, void* d_ws, size_t ws_size,
                              hipStream_t stream)
{
    const float* x  = (const float*)d_in[0];  // [2,2048,1024] f32
    const float* wq = (const float*)d_in[1];  // [1024,3072] f32
    float* out = (float*)d_out;               // [2,2048,1024] f32

    const size_t HEADTEN = (size_t)32 * 2048 * 64;   // 8.4 MB bf16 each
    ushort* wsp = (ushort*)d_ws;
    ushort* qh = wsp;
    ushort* kh = qh + HEADTEN;
    ushort* vt = kh + HEADTEN;
    ushort* xb = vt + HEADTEN;           // dead after GEMM
    ushort* wt = xb + (size_t)GM * GK;   // dead after GEMM
    ushort* opart = xb;                               // s0,s1 partials (16.8 MB)
    float*  lp    = (float*)(opart + (size_t)2 * NROWS * 64);   // Lp[4][NROWS] (1 MB)

    conv_fused<<<2816, 256, 0, stream>>>(x, wq, xb, wt);
    qkv_gemm_bf16<<<256, 512, 0, stream>>>(xb, wt, qh, kh, vt);
    attn_bf16<<<1024, 512, 0, stream>>>(qh, kh, vt, opart, lp, out);
    attn_combine<<<NROWS * 16 / 256, 256, 0, stream>>>(opart, lp, out);
}

// Round 12
// 188.397 us; speedup vs baseline: 1.1202x; 1.1202x over previous
//
#include <hip/hip_runtime.h>
#include <hip/hip_bf16.h>
#include <math.h>

// B=2, L=2048, D=1024, H=16, HD=64
#define NB_L 2048
#define GM 4096          // B*L rows
#define GN 3072          // 3*D cols
#define GK 1024
#define NROWS 65536      // B*H*L partial rows per split
#define SCALE_L2E 0.180336880f   // 0.125 * log2(e), folded into Q at GEMM epilogue

typedef float  f4v __attribute__((ext_vector_type(4)));
typedef short  s4v __attribute__((ext_vector_type(4)));
typedef short  s8v __attribute__((ext_vector_type(8)));

#define MFMA_16x16x32(a, b, c) __builtin_amdgcn_mfma_f32_16x16x32_bf16((a), (b), (c), 0, 0, 0)
#define MFMA_16x16x16(a, b, c) __builtin_amdgcn_mfma_f32_16x16x16bf16_1k((a), (b), (c), 0, 0, 0)

static __device__ __forceinline__ unsigned int bfpk(float a, float b) {
    __hip_bfloat162 h = __float22bfloat162_rn(float2{a, b});
    union { __hip_bfloat162 h2; unsigned int u; } cv; cv.h2 = h; return cv.u;
}
// Fast f32x2 -> packed bf16x2 (round-half-up via +0x8000, then byte-perm).
static __device__ __forceinline__ unsigned int pkrnd(float a, float b) {
    union { float f; unsigned int u; } ua, ub;
    ua.f = a; ub.f = b;
    return __builtin_amdgcn_perm(ub.u + 0x8000u, ua.u + 0x8000u, 0x07060302u);
}
static __device__ __forceinline__ unsigned short bf1(float a) {
    union { __hip_bfloat16 h; unsigned short u; } cv; cv.h = __float2bfloat16(a); return cv.u;
}
static __device__ __forceinline__ float bf2f(unsigned short u) {
    union { unsigned int u; float f; } cv; cv.u = ((unsigned int)u) << 16; return cv.f;
}

// async global->LDS, 16B per lane
static __device__ __forceinline__ void gl_lds16(const ushort* g, ushort* l) {
    __builtin_amdgcn_global_load_lds((const __attribute__((address_space(1))) void*)g,
                                     (__attribute__((address_space(3))) void*)l, 16, 0, 0);
}

// ---------------------------------------------------------------------------
// Fused input prep: blocks [0,2048) convert X f32->bf16; blocks [2048,2816)
// convert+transpose W -> Wt [3072,1024] bf16 (k contiguous).
// ---------------------------------------------------------------------------
__global__ __launch_bounds__(256) void conv_fused(
    const float* __restrict__ X, const float* __restrict__ W,
    ushort* __restrict__ Xb, ushort* __restrict__ Wt)
{
    __shared__ __align__(16) ushort T[64][72];
    const int bid = blockIdx.x, t = threadIdx.x;
    if (bid < 2048) {
        const int i = bid * 256 + t;
        const float4 f0 = ((const float4*)X)[2 * i];
        const float4 f1 = ((const float4*)X)[2 * i + 1];
        uint4 u;
        u.x = bfpk(f0.x, f0.y); u.y = bfpk(f0.z, f0.w);
        u.z = bfpk(f1.x, f1.y); u.w = bfpk(f1.z, f1.w);
        ((uint4*)Xb)[i] = u;
    } else {
        const int wb = bid - 2048;                 // 0..767
        const int k0 = (wb & 15) * 64, n0 = (wb >> 4) * 64;
        {
            const int kr = t >> 2, nc0 = (t & 3) * 16;
            const float* src = W + (size_t)(k0 + kr) * GN + n0 + nc0;
#pragma unroll
            for (int u = 0; u < 4; ++u) {
                const float4 v = *(const float4*)(src + 4 * u);
                T[nc0 + 4 * u + 0][kr] = bf1(v.x);
                T[nc0 + 4 * u + 1][kr] = bf1(v.y);
                T[nc0 + 4 * u + 2][kr] = bf1(v.z);
                T[nc0 + 4 * u + 3][kr] = bf1(v.w);
            }
        }
        __syncthreads();
        {
            const int nr = t >> 2, kc0 = (t & 3) * 16;
            ushort* dst = Wt + (size_t)(n0 + nr) * GK + k0 + kc0;
            *(s8v*)dst       = *(const s8v*)&T[nr][kc0];
            *(s8v*)(dst + 8) = *(const s8v*)&T[nr][kc0 + 8];
        }
    }
}

// ---------------------------------------------------------------------------
// bf16 MFMA GEMM — round-3 4-phase version, byte-identical (replication
// probe continues for the 48-vs-69 us question; VGPR 104/96 flapped with
// zero source change = co-compile perturbation).
// BM=128 x BN=384, BK=64, 512 thr (8 waves, 2M x 4N), 128 KiB LDS,
// grid 32x8 = 256 blocks = exactly 1/CU; chunk-XOR swizzle (0 conflicts).
// ---------------------------------------------------------------------------
__global__ __launch_bounds__(512, 2) void qkv_gemm_bf16(
    const ushort* __restrict__ Xb, const ushort* __restrict__ Wt,
    ushort* __restrict__ Qh, ushort* __restrict__ Kh, ushort* __restrict__ VT)
{
    __shared__ __align__(16) ushort As[2][2][128][32];   // 32 KB [buf][khalf][row][k]
    __shared__ __align__(16) ushort Bs[2][2][384][32];   // 96 KB

    const int tid = threadIdx.x;
    const int bid = blockIdx.x;

    // XCD region swizzle: tile grid 32(y) x 8(x); xcd owns 8y x 4x region
    const int xcd = bid & 7, idx = bid >> 3;             // idx in [0,32)
    const int ytile = ((xcd >> 1) << 3) + (idx & 7);     // 0..31
    const int xtile = ((xcd & 1) << 2) + (idx >> 3);     // 0..7
    const int row0 = ytile << 7;                         // *128
    const int col0 = xtile * 384;

    const int lane = tid & 63, w = tid >> 6;
    const int wm = w >> 2, wn = w & 3;                   // 2M x 4N wave grid
    const int lq = lane & 15, quad = lane >> 4;

    // staging decomposition: thread -> (row-within-issue rS, physical chunk pA)
    const int rS = tid >> 2, pA = tid & 3;               // rS in [0,128)
    const int cA = pA ^ ((rS >> 1) & 3);                 // logical chunk (inverse swizzle)
    const ushort* gA0 = Xb + (size_t)(row0 + rS) * GK + cA * 8;
    const ushort* gB0 = Wt + (size_t)(col0 + rS) * GK + cA * 8;

    // frag-read physical chunk (element offset within 32-k row)
    const int pq = (quad ^ ((lq >> 1) & 3)) * 8;
    const int rowA = wm * 64 + lq;
    const int rowB = wn * 96 + lq;

    f4v acc[4][6];
#pragma unroll
    for (int mf = 0; mf < 4; ++mf)
#pragma unroll
        for (int nf = 0; nf < 6; ++nf) acc[mf][nf] = 0.f;

    auto stA = [&](int t, int h) {
        gl_lds16(gA0 + t * 64 + h * 32, &As[t & 1][h][rS][pA * 8]);
    };
    auto stB = [&](int t, int h, int u) {
        gl_lds16(gB0 + (size_t)u * 128 * GK + t * 64 + h * 32,
                 &Bs[t & 1][h][u * 128 + rS][pA * 8]);
    };

    // prologue: t0 fully + t1 kh0 last; newest 4 (t1 kh0 group) stay in flight
    stA(0, 0);
    stB(0, 0, 0); stB(0, 0, 1); stB(0, 0, 2);
    stA(0, 1);
    stB(0, 1, 0); stB(0, 1, 1); stB(0, 1, 2);
    stA(1, 0);
    stB(1, 0, 0); stB(1, 0, 1); stB(1, 0, 2);
    asm volatile("s_waitcnt vmcnt(4)" ::: "memory");
    __builtin_amdgcn_s_barrier();
    asm volatile("" ::: "memory");

    const int NT = GK / 64;   // 16
#pragma unroll 2
    for (int t = 0; t < NT; ++t) {
        const int cur = t & 1;
        s8v af[4], bfr[3];

        // ---- phase 0: kh0, N-lo ----
#pragma unroll
        for (int nf = 0; nf < 3; ++nf) bfr[nf] = *(const s8v*)&Bs[cur][0][rowB + nf * 16][pq];
#pragma unroll
        for (int mf = 0; mf < 4; ++mf) af[mf] = *(const s8v*)&As[cur][0][rowA + mf * 16][pq];
        if (t + 1 < NT) { stB(t + 1, 1, 0); stB(t + 1, 1, 1); stB(t + 1, 1, 2); }
        __builtin_amdgcn_s_barrier();
        asm volatile("s_waitcnt lgkmcnt(0)");
        __builtin_amdgcn_s_setprio(1);
#pragma unroll
        for (int mf = 0; mf < 4; ++mf)
#pragma unroll
            for (int nf = 0; nf < 3; ++nf)
                acc[mf][nf] = MFMA_16x16x32(af[mf], bfr[nf], acc[mf][nf]);
        __builtin_amdgcn_s_setprio(0);
        __builtin_amdgcn_s_barrier();

        // ---- phase 1: kh0, N-hi (A frags reused) ----
#pragma unroll
        for (int nf = 0; nf < 3; ++nf) bfr[nf] = *(const s8v*)&Bs[cur][0][rowB + 48 + nf * 16][pq];
        if (t + 1 < NT) stA(t + 1, 1);
        __builtin_amdgcn_s_barrier();
        asm volatile("s_waitcnt lgkmcnt(0)");
        __builtin_amdgcn_s_setprio(1);
#pragma unroll
        for (int mf = 0; mf < 4; ++mf)
#pragma unroll
            for (int nf = 0; nf < 3; ++nf)
                acc[mf][nf + 3] = MFMA_16x16x32(af[mf], bfr[nf], acc[mf][nf + 3]);
        __builtin_amdgcn_s_setprio(0);
        __builtin_amdgcn_s_barrier();

        // ---- phase 2: kh1, N-lo ----
#pragma unroll
        for (int nf = 0; nf < 3; ++nf) bfr[nf] = *(const s8v*)&Bs[cur][1][rowB + nf * 16][pq];
#pragma unroll
        for (int mf = 0; mf < 4; ++mf) af[mf] = *(const s8v*)&As[cur][1][rowA + mf * 16][pq];
        if (t + 2 < NT) stA(t + 2, 0);   // cur-buf kh0: last read was ph0
        __builtin_amdgcn_s_barrier();
        asm volatile("s_waitcnt lgkmcnt(0)");
        __builtin_amdgcn_s_setprio(1);
#pragma unroll
        for (int mf = 0; mf < 4; ++mf)
#pragma unroll
            for (int nf = 0; nf < 3; ++nf)
                acc[mf][nf] = MFMA_16x16x32(af[mf], bfr[nf], acc[mf][nf]);
        __builtin_amdgcn_s_setprio(0);
        __builtin_amdgcn_s_barrier();

        // ---- phase 3: kh1, N-hi ----
#pragma unroll
        for (int nf = 0; nf < 3; ++nf) bfr[nf] = *(const s8v*)&Bs[cur][1][rowB + 48 + nf * 16][pq];
        if (t + 2 < NT) { stB(t + 2, 0, 0); stB(t + 2, 0, 1); stB(t + 2, 0, 2); }
        __builtin_amdgcn_s_barrier();
        asm volatile("s_waitcnt lgkmcnt(0)");
        __builtin_amdgcn_s_setprio(1);
#pragma unroll
        for (int mf = 0; mf < 4; ++mf)
#pragma unroll
            for (int nf = 0; nf < 3; ++nf)
                acc[mf][nf + 3] = MFMA_16x16x32(af[mf], bfr[nf], acc[mf][nf + 3]);
        __builtin_amdgcn_s_setprio(0);
        // keep the newest 4 (t+2 kh0 group) in flight; drain only in tail
        if (t + 2 < NT) asm volatile("s_waitcnt vmcnt(4)" ::: "memory");
        else            asm volatile("s_waitcnt vmcnt(0)" ::: "memory");
        __builtin_amdgcn_s_barrier();
        asm volatile("" ::: "memory");
    }

    // epilogue: row = row0 + wm*64 + mf*16 + quad*4 + r
    //           col = col0 + wn*96 + nf*16 + lq
#pragma unroll
    for (int mf = 0; mf < 4; ++mf)
#pragma unroll
        for (int nf = 0; nf < 6; ++nf) {
            const int colg = col0 + wn * 96 + nf * 16 + lq;
            const int part = colg >> 10;          // uniform per nf-frag (16 | 1024)
            const int colp = colg & 1023;
            const int hh = colp >> 6, d = colp & 63;
#pragma unroll
            for (int r = 0; r < 4; ++r) {
                const int row = row0 + wm * 64 + mf * 16 + quad * 4 + r;
                const int b = row >> 11, tok = row & 2047;
                const int bh = b * 16 + hh;
                if (part == 0) {
                    Qh[((size_t)bh * 2048 + tok) * 64 + d] = bf1(acc[mf][nf][r] * SCALE_L2E);
                } else if (part == 1) {
                    Kh[((size_t)bh * 2048 + tok) * 64 + (d ^ ((tok & 7) << 3))] = bf1(acc[mf][nf][r]);
                } else {
                    VT[((size_t)bh * 64 + d) * 2048 + (tok ^ ((d & 7) << 3))] = bf1(acc[mf][nf][r]);
                }
            }
        }
}

// ---------------------------------------------------------------------------
// Flash attention — round-12: K-split=4 RETAINED, launch bound RELAXED.
//
// r11 counters: Occupancy 63% (residency theory CONFIRMED) but VGPR pinned
// 64->32 by __launch_bounds__(512,8) -> massive scratch spill (FETCH 19->80
// MB, WRITE 27->84 MB, HBM 1.96 TB/s) -> 85.9 us.  The bound, not the
// split, caused the regression.  (512,4) lets the allocator land at its
// natural ~64 VGPR (r10 compiled to exactly 64): 64 VGPR = 8 waves/SIMD
// boundary -> HW can still host 4 blocks/CU x 8 waves = 32 waves/CU with
// zero spill.  Even at ~80 VGPR we get 24 waves/CU (1.5x r10).
//
// Work split (unchanged from r11): (bh, qt, s): kt in [s*T/4,(s+1)*T/4),
// T=2qt+2; pieces {qp,15-qp}; s2,s3 partials packed into Out's f32 slots.
// ---------------------------------------------------------------------------
__global__ __launch_bounds__(512, 4) void attn_bf16(
    const ushort* __restrict__ Qh, const ushort* __restrict__ Kh,
    const ushort* __restrict__ VT, ushort* __restrict__ Opart,
    float* __restrict__ Lp, float* __restrict__ OutS)
{
    __shared__ __align__(16) ushort Ks[2][64 * 64];   // [krow][d^swz]
    __shared__ __align__(16) ushort Vt[2][64 * 64];   // [d][k^swz]

    const int x = blockIdx.x;            // 1024 blocks
    const int bh = x & 31;               // same-bh blocks share an XCD (x%8==bh%8)
    const int y = x >> 5;                // [0,32)
    const int s = y & 3;                 // K-quarter
    const int qp = y >> 2;               // [0,8)

    const int tid = threadIdx.x;
    const int w = tid >> 6, lane = tid & 63;   // w in [0,8)
    const int lq = lane & 15, quad = lane >> 4;
    const int kswz = (lq & 7) << 3;

    const ushort* kbase = Kh + (size_t)bh * 2048 * 64;
    const ushort* vbase = VT + (size_t)bh * 64 * 2048;
    // staging: 512 thr x 16B = 8 KB = one full 64x64 bf16 tile per issue
    const int kr = tid >> 3, ko = (tid & 7) * 8;      // kr in [0,64)

    auto stage = [&](int kt, int bufi) {
        gl_lds16(kbase + (size_t)kt * 64 * 64 + kr * 64 + ko, &Ks[bufi][tid * 8]);
        gl_lds16(vbase + (size_t)kr * 2048 + kt * 64 + ko,    &Vt[bufi][tid * 8]);
    };

    const s4v ones = { (short)0x3F80, (short)0x3F80, (short)0x3F80, (short)0x3F80 };

#pragma unroll 1
    for (int piece = 0; piece < 2; ++piece) {
        const int qt = piece ? (15 - qp) : qp;
        const int qrow_base = qt * 128 + w * 16;      // 8 waves x 16 rows
        const int diag = 2 * qt + (w >> 2);           // wave's diagonal K-tile
        const int T = 2 * qt + 2;                     // total K-tiles for qt
        const int kt_lo = (s * T) >> 2;
        const int kt_hi = ((s + 1) * T) >> 2;
        const int niter = kt_hi - kt_lo;              // may be 0

        // piece 2: ensure all waves finished piece-1 reads before buf0 reuse
        if (piece) __builtin_amdgcn_s_barrier();

        s8v qf[2];
#pragma unroll
        for (int sb = 0; sb < 2; ++sb)
            qf[sb] = *(const s8v*)(Qh + ((size_t)bh * 2048 + qrow_base + lq) * 64
                                   + sb * 32 + quad * 8);

        f4v o[4];
#pragma unroll
        for (int dg = 0; dg < 4; ++dg) o[dg] = 0.f;
        f4v lacc = 0.f;

        auto compute = [&](int ktc, int bufi) {
            if (ktc > diag) return;
            f4v st[4];
#pragma unroll
            for (int kg = 0; kg < 4; ++kg) st[kg] = 0.f;
#pragma unroll
            for (int kg = 0; kg < 4; ++kg)
#pragma unroll
                for (int sb = 0; sb < 2; ++sb) {
                    const s8v af = *(const s8v*)&Ks[bufi][(kg * 16 + lq) * 64
                                                         + ((sb * 32 + quad * 8) ^ kswz)];
                    st[kg] = MFMA_16x16x32(af, qf[sb], st[kg]);
                }
            if (ktc == diag) {
                const int qrow = qrow_base + lq;
#pragma unroll
                for (int kg = 0; kg < 4; ++kg)
#pragma unroll
                    for (int r = 0; r < 4; ++r)
                        if (ktc * 64 + kg * 16 + quad * 4 + r > qrow)
                            st[kg][r] = -INFINITY;
            }
#pragma unroll
            for (int kg = 0; kg < 4; ++kg)
#pragma unroll
                for (int r = 0; r < 4; ++r)
                    st[kg][r] = exp2f(st[kg][r]);
#pragma unroll
            for (int ks = 0; ks < 4; ++ks) {
                s4v pb;
                {
                    union { s4v v; uint2 u; } c;
                    c.u.x = pkrnd(st[ks][0], st[ks][1]);
                    c.u.y = pkrnd(st[ks][2], st[ks][3]);
                    pb = c.v;
                }
                lacc = MFMA_16x16x16(ones, pb, lacc);
#pragma unroll
                for (int dg = 0; dg < 4; ++dg) {
                    const s4v va = *(const s4v*)&Vt[bufi][(dg * 16 + lq) * 64
                                                         + ((ks * 16 + quad * 4) ^ kswz)];
                    o[dg] = MFMA_16x16x16(va, pb, o[dg]);
                }
            }
        };

        if (niter > 0) {
            stage(kt_lo, 0);                           // 2 loads in flight
#pragma unroll 1
            for (int i = 0; i < niter; ++i) {
                const int cur = i & 1;
                __builtin_amdgcn_s_barrier();          // B1: all compute(i-1) done
                if (i + 1 < niter) {
                    stage(kt_lo + i + 1, cur ^ 1);     // +2 -> 4 outstanding
                    asm volatile("s_waitcnt vmcnt(2)" ::: "memory");   // retire buf-i's 2
                } else {
                    asm volatile("s_waitcnt vmcnt(0)" ::: "memory");   // piece tail drain
                }
                __builtin_amdgcn_s_barrier();          // B2: everyone's buf-i landed
                compute(kt_lo + i, cur);
            }
        }

        // piece epilogue: wave writes its 16 rows for this split
        {
            const int qrow = qrow_base + lq;
            const size_t prow = (size_t)(s * 32 + bh) * 2048 + qrow;   // = s*NROWS + row
            if (s < 2) {
#pragma unroll
                for (int dg = 0; dg < 4; ++dg) {
                    const int d = dg * 16 + quad * 4;
                    uint2 u;
                    u.x = bfpk(o[dg][0], o[dg][1]);
                    u.y = bfpk(o[dg][2], o[dg][3]);
                    *(uint2*)&Opart[prow * 64 + d] = u;
                }
            } else {
                // pack into Out f32 slots: low ushort = s2, high ushort = s3
                const int b_ = bh >> 4, h = bh & 15;
                const size_t fbase = ((size_t)(b_ * 2048 + qrow)) * 1024 + h * 64;
                ushort* op = (ushort*)OutS;
                const int hilo = s & 1;
#pragma unroll
                for (int dg = 0; dg < 4; ++dg) {
                    const int d = dg * 16 + quad * 4;
#pragma unroll
                    for (int r = 0; r < 4; ++r)
                        op[2 * (fbase + d + r) + hilo] = bf1(o[dg][r]);
                }
            }
            if (quad == 0) Lp[prow] = lacc[0];
        }
    }
}

// ---------------------------------------------------------------------------
// Combine the four K-split partials -> final f32 output [B, L, D].
// s0,s1 from Opart/ws; s2,s3 read from Out's own slots (then overwritten).
// ---------------------------------------------------------------------------
__global__ __launch_bounds__(256) void attn_combine(
    const ushort* __restrict__ Opart, const float* __restrict__ Lp, float* __restrict__ Out)
{
    const int id = blockIdx.x * 256 + threadIdx.x;
    const int row = id >> 4, c4 = (id & 15) * 4;
    const float l = Lp[row] + Lp[row + NROWS] + Lp[row + 2 * NROWS] + Lp[row + 3 * NROWS];
    const float inv = 1.0f / l;

    const s4v a = *(const s4v*)&Opart[(size_t)row * 64 + c4];
    const s4v c = *(const s4v*)&Opart[(size_t)(row + NROWS) * 64 + c4];

    const int bh = row >> 11, qrow = row & 2047;
    const int b = bh >> 4, h = bh & 15;
    float* outp = Out + ((size_t)(b * 2048 + qrow)) * 1024 + h * 64 + c4;
    const uint4 slot = *(const uint4*)outp;   // packed {s2,s3} bf16 halves

    float4 v;
    v.x = (bf2f((unsigned short)a[0]) + bf2f((unsigned short)c[0])
         + bf2f((unsigned short)(slot.x & 0xffff)) + bf2f((unsigned short)(slot.x >> 16))) * inv;
    v.y = (bf2f((unsigned short)a[1]) + bf2f((unsigned short)c[1])
         + bf2f((unsigned short)(slot.y & 0xffff)) + bf2f((unsigned short)(slot.y >> 16))) * inv;
    v.z = (bf2f((unsigned short)a[2]) + bf2f((unsigned short)c[2])
         + bf2f((unsigned short)(slot.z & 0xffff)) + bf2f((unsigned short)(slot.z >> 16))) * inv;
    v.w = (bf2f((unsigned short)a[3]) + bf2f((unsigned short)c[3])
         + bf2f((unsigned short)(slot.w & 0xffff)) + bf2f((unsigned short)(slot.w >> 16))) * inv;

    *(float4*)outp = v;
}

// ---------------------------------------------------------------------------
extern "C" void kernel_launch(void* const* d_in, const int* in_sizes, int n_in,
                              void* d_out, int out_size, void* d_ws, size_t ws_size,
                              hipStream_t stream)
{
    const float* x  = (const float*)d_in[0];  // [2,2048,1024] f32
    const float* wq = (const float*)d_in[1];  // [1024,3072] f32
    float* out = (float*)d_out;               // [2,2048,1024] f32

    const size_t HEADTEN = (size_t)32 * 2048 * 64;   // 8.4 MB bf16 each
    ushort* wsp = (ushort*)d_ws;
    ushort* qh = wsp;
    ushort* kh = qh + HEADTEN;
    ushort* vt = kh + HEADTEN;
    ushort* xb = vt + HEADTEN;           // dead after GEMM
    ushort* wt = xb + (size_t)GM * GK;   // dead after GEMM
    ushort* opart = xb;                               // s0,s1 partials (16.8 MB)
    float*  lp    = (float*)(opart + (size_t)2 * NROWS * 64);   // Lp[4][NROWS] (1 MB)

    conv_fused<<<2816, 256, 0, stream>>>(x, wq, xb, wt);
    qkv_gemm_bf16<<<256, 512, 0, stream>>>(xb, wt, qh, kh, vt);
    attn_bf16<<<1024, 512, 0, stream>>>(qh, kh, vt, opart, lp, out);
    attn_combine<<<NROWS * 16 / 256, 256, 0, stream>>>(opart, lp, out);
}

// Round 13
// 163.861 us; speedup vs baseline: 1.2879x; 1.1497x over previous
//
#include <hip/hip_runtime.h>
#include <hip/hip_bf16.h>
#include <math.h>

// B=2, L=2048, D=1024, H=16, HD=64
#define NB_L 2048
#define GM 4096          // B*L rows
#define GN 3072          // 3*D cols
#define GK 1024
#define NROWS 65536      // B*H*L partial rows per split
#define SCALE_L2E 0.180336880f   // 0.125 * log2(e), folded into Q at GEMM epilogue

typedef float  f4v __attribute__((ext_vector_type(4)));
typedef short  s4v __attribute__((ext_vector_type(4)));
typedef short  s8v __attribute__((ext_vector_type(8)));

#define MFMA_16x16x32(a, b, c) __builtin_amdgcn_mfma_f32_16x16x32_bf16((a), (b), (c), 0, 0, 0)
#define MFMA_16x16x16(a, b, c) __builtin_amdgcn_mfma_f32_16x16x16bf16_1k((a), (b), (c), 0, 0, 0)

static __device__ __forceinline__ unsigned int bfpk(float a, float b) {
    __hip_bfloat162 h = __float22bfloat162_rn(float2{a, b});
    union { __hip_bfloat162 h2; unsigned int u; } cv; cv.h2 = h; return cv.u;
}
// Fast f32x2 -> packed bf16x2 (round-half-up via +0x8000, then byte-perm).
// Kept from r9: neutral perf, identical absmax, 3 VALU ops/pair.
static __device__ __forceinline__ unsigned int pkrnd(float a, float b) {
    union { float f; unsigned int u; } ua, ub;
    ua.f = a; ub.f = b;
    return __builtin_amdgcn_perm(ub.u + 0x8000u, ua.u + 0x8000u, 0x07060302u);
}
static __device__ __forceinline__ unsigned short bf1(float a) {
    union { __hip_bfloat16 h; unsigned short u; } cv; cv.h = __float2bfloat16(a); return cv.u;
}
static __device__ __forceinline__ float bf2f(unsigned short u) {
    union { unsigned int u; float f; } cv; cv.u = ((unsigned int)u) << 16; return cv.f;
}

// async global->LDS, 16B per lane
static __device__ __forceinline__ void gl_lds16(const ushort* g, ushort* l) {
    __builtin_amdgcn_global_load_lds((const __attribute__((address_space(1))) void*)g,
                                     (__attribute__((address_space(3))) void*)l, 16, 0, 0);
}

// ---------------------------------------------------------------------------
// Fused input prep: blocks [0,2048) convert X f32->bf16; blocks [2048,2816)
// convert+transpose W -> Wt [3072,1024] bf16 (k contiguous).
// ---------------------------------------------------------------------------
__global__ __launch_bounds__(256) void conv_fused(
    const float* __restrict__ X, const float* __restrict__ W,
    ushort* __restrict__ Xb, ushort* __restrict__ Wt)
{
    __shared__ __align__(16) ushort T[64][72];
    const int bid = blockIdx.x, t = threadIdx.x;
    if (bid < 2048) {
        const int i = bid * 256 + t;
        const float4 f0 = ((const float4*)X)[2 * i];
        const float4 f1 = ((const float4*)X)[2 * i + 1];
        uint4 u;
        u.x = bfpk(f0.x, f0.y); u.y = bfpk(f0.z, f0.w);
        u.z = bfpk(f1.x, f1.y); u.w = bfpk(f1.z, f1.w);
        ((uint4*)Xb)[i] = u;
    } else {
        const int wb = bid - 2048;                 // 0..767
        const int k0 = (wb & 15) * 64, n0 = (wb >> 4) * 64;
        {
            const int kr = t >> 2, nc0 = (t & 3) * 16;
            const float* src = W + (size_t)(k0 + kr) * GN + n0 + nc0;
#pragma unroll
            for (int u = 0; u < 4; ++u) {
                const float4 v = *(const float4*)(src + 4 * u);
                T[nc0 + 4 * u + 0][kr] = bf1(v.x);
                T[nc0 + 4 * u + 1][kr] = bf1(v.y);
                T[nc0 + 4 * u + 2][kr] = bf1(v.z);
                T[nc0 + 4 * u + 3][kr] = bf1(v.w);
            }
        }
        __syncthreads();
        {
            const int nr = t >> 2, kc0 = (t & 3) * 16;
            ushort* dst = Wt + (size_t)(n0 + nr) * GK + k0 + kc0;
            *(s8v*)dst       = *(const s8v*)&T[nr][kc0];
            *(s8v*)(dst + 8) = *(const s8v*)&T[nr][kc0 + 8];
        }
    }
}

// ---------------------------------------------------------------------------
// bf16 MFMA GEMM — round-3 4-phase version (best measured ~48 us; r8's
// single-barrier depth-3 regressed, so barrier structure is not the lever).
// BM=128 x BN=384, BK=64, 512 thr (8 waves, 2M x 4N), 128 KiB LDS,
// grid 32x8 = 256 blocks = exactly 1/CU; chunk-XOR swizzle (0 conflicts).
// ---------------------------------------------------------------------------
__global__ __launch_bounds__(512, 2) void qkv_gemm_bf16(
    const ushort* __restrict__ Xb, const ushort* __restrict__ Wt,
    ushort* __restrict__ Qh, ushort* __restrict__ Kh, ushort* __restrict__ VT)
{
    __shared__ __align__(16) ushort As[2][2][128][32];   // 32 KB [buf][khalf][row][k]
    __shared__ __align__(16) ushort Bs[2][2][384][32];   // 96 KB

    const int tid = threadIdx.x;
    const int bid = blockIdx.x;

    // XCD region swizzle: tile grid 32(y) x 8(x); xcd owns 8y x 4x region
    const int xcd = bid & 7, idx = bid >> 3;             // idx in [0,32)
    const int ytile = ((xcd >> 1) << 3) + (idx & 7);     // 0..31
    const int xtile = ((xcd & 1) << 2) + (idx >> 3);     // 0..7
    const int row0 = ytile << 7;                         // *128
    const int col0 = xtile * 384;

    const int lane = tid & 63, w = tid >> 6;
    const int wm = w >> 2, wn = w & 3;                   // 2M x 4N wave grid
    const int lq = lane & 15, quad = lane >> 4;

    // staging decomposition: thread -> (row-within-issue rS, physical chunk pA)
    const int rS = tid >> 2, pA = tid & 3;               // rS in [0,128)
    const int cA = pA ^ ((rS >> 1) & 3);                 // logical chunk (inverse swizzle)
    const ushort* gA0 = Xb + (size_t)(row0 + rS) * GK + cA * 8;
    const ushort* gB0 = Wt + (size_t)(col0 + rS) * GK + cA * 8;

    // frag-read physical chunk (element offset within 32-k row)
    const int pq = (quad ^ ((lq >> 1) & 3)) * 8;
    const int rowA = wm * 64 + lq;
    const int rowB = wn * 96 + lq;

    f4v acc[4][6];
#pragma unroll
    for (int mf = 0; mf < 4; ++mf)
#pragma unroll
        for (int nf = 0; nf < 6; ++nf) acc[mf][nf] = 0.f;

    auto stA = [&](int t, int h) {
        gl_lds16(gA0 + t * 64 + h * 32, &As[t & 1][h][rS][pA * 8]);
    };
    auto stB = [&](int t, int h, int u) {
        gl_lds16(gB0 + (size_t)u * 128 * GK + t * 64 + h * 32,
                 &Bs[t & 1][h][u * 128 + rS][pA * 8]);
    };

    // prologue: t0 fully + t1 kh0 last; newest 4 (t1 kh0 group) stay in flight
    stA(0, 0);
    stB(0, 0, 0); stB(0, 0, 1); stB(0, 0, 2);
    stA(0, 1);
    stB(0, 1, 0); stB(0, 1, 1); stB(0, 1, 2);
    stA(1, 0);
    stB(1, 0, 0); stB(1, 0, 1); stB(1, 0, 2);
    asm volatile("s_waitcnt vmcnt(4)" ::: "memory");
    __builtin_amdgcn_s_barrier();
    asm volatile("" ::: "memory");

    const int NT = GK / 64;   // 16
#pragma unroll 2
    for (int t = 0; t < NT; ++t) {
        const int cur = t & 1;
        s8v af[4], bfr[3];

        // ---- phase 0: kh0, N-lo ----
#pragma unroll
        for (int nf = 0; nf < 3; ++nf) bfr[nf] = *(const s8v*)&Bs[cur][0][rowB + nf * 16][pq];
#pragma unroll
        for (int mf = 0; mf < 4; ++mf) af[mf] = *(const s8v*)&As[cur][0][rowA + mf * 16][pq];
        if (t + 1 < NT) { stB(t + 1, 1, 0); stB(t + 1, 1, 1); stB(t + 1, 1, 2); }
        __builtin_amdgcn_s_barrier();
        asm volatile("s_waitcnt lgkmcnt(0)");
        __builtin_amdgcn_s_setprio(1);
#pragma unroll
        for (int mf = 0; mf < 4; ++mf)
#pragma unroll
            for (int nf = 0; nf < 3; ++nf)
                acc[mf][nf] = MFMA_16x16x32(af[mf], bfr[nf], acc[mf][nf]);
        __builtin_amdgcn_s_setprio(0);
        __builtin_amdgcn_s_barrier();

        // ---- phase 1: kh0, N-hi (A frags reused) ----
#pragma unroll
        for (int nf = 0; nf < 3; ++nf) bfr[nf] = *(const s8v*)&Bs[cur][0][rowB + 48 + nf * 16][pq];
        if (t + 1 < NT) stA(t + 1, 1);
        __builtin_amdgcn_s_barrier();
        asm volatile("s_waitcnt lgkmcnt(0)");
        __builtin_amdgcn_s_setprio(1);
#pragma unroll
        for (int mf = 0; mf < 4; ++mf)
#pragma unroll
            for (int nf = 0; nf < 3; ++nf)
                acc[mf][nf + 3] = MFMA_16x16x32(af[mf], bfr[nf], acc[mf][nf + 3]);
        __builtin_amdgcn_s_setprio(0);
        __builtin_amdgcn_s_barrier();

        // ---- phase 2: kh1, N-lo ----
#pragma unroll
        for (int nf = 0; nf < 3; ++nf) bfr[nf] = *(const s8v*)&Bs[cur][1][rowB + nf * 16][pq];
#pragma unroll
        for (int mf = 0; mf < 4; ++mf) af[mf] = *(const s8v*)&As[cur][1][rowA + mf * 16][pq];
        if (t + 2 < NT) stA(t + 2, 0);   // cur-buf kh0: last read was ph0
        __builtin_amdgcn_s_barrier();
        asm volatile("s_waitcnt lgkmcnt(0)");
        __builtin_amdgcn_s_setprio(1);
#pragma unroll
        for (int mf = 0; mf < 4; ++mf)
#pragma unroll
            for (int nf = 0; nf < 3; ++nf)
                acc[mf][nf] = MFMA_16x16x32(af[mf], bfr[nf], acc[mf][nf]);
        __builtin_amdgcn_s_setprio(0);
        __builtin_amdgcn_s_barrier();

        // ---- phase 3: kh1, N-hi ----
#pragma unroll
        for (int nf = 0; nf < 3; ++nf) bfr[nf] = *(const s8v*)&Bs[cur][1][rowB + 48 + nf * 16][pq];
        if (t + 2 < NT) { stB(t + 2, 0, 0); stB(t + 2, 0, 1); stB(t + 2, 0, 2); }
        __builtin_amdgcn_s_barrier();
        asm volatile("s_waitcnt lgkmcnt(0)");
        __builtin_amdgcn_s_setprio(1);
#pragma unroll
        for (int mf = 0; mf < 4; ++mf)
#pragma unroll
            for (int nf = 0; nf < 3; ++nf)
                acc[mf][nf + 3] = MFMA_16x16x32(af[mf], bfr[nf], acc[mf][nf + 3]);
        __builtin_amdgcn_s_setprio(0);
        // keep the newest 4 (t+2 kh0 group) in flight; drain only in tail
        if (t + 2 < NT) asm volatile("s_waitcnt vmcnt(4)" ::: "memory");
        else            asm volatile("s_waitcnt vmcnt(0)" ::: "memory");
        __builtin_amdgcn_s_barrier();
        asm volatile("" ::: "memory");
    }

    // epilogue: row = row0 + wm*64 + mf*16 + quad*4 + r
    //           col = col0 + wn*96 + nf*16 + lq
#pragma unroll
    for (int mf = 0; mf < 4; ++mf)
#pragma unroll
        for (int nf = 0; nf < 6; ++nf) {
            const int colg = col0 + wn * 96 + nf * 16 + lq;
            const int part = colg >> 10;          // uniform per nf-frag (16 | 1024)
            const int colp = colg & 1023;
            const int hh = colp >> 6, d = colp & 63;
#pragma unroll
            for (int r = 0; r < 4; ++r) {
                const int row = row0 + wm * 64 + mf * 16 + quad * 4 + r;
                const int b = row >> 11, tok = row & 2047;
                const int bh = b * 16 + hh;
                if (part == 0) {
                    Qh[((size_t)bh * 2048 + tok) * 64 + d] = bf1(acc[mf][nf][r] * SCALE_L2E);
                } else if (part == 1) {
                    Kh[((size_t)bh * 2048 + tok) * 64 + (d ^ ((tok & 7) << 3))] = bf1(acc[mf][nf][r]);
                } else {
                    VT[((size_t)bh * 64 + d) * 2048 + (tok ^ ((d & 7) << 3))] = bf1(acc[mf][nf][r]);
                }
            }
        }
}

// ---------------------------------------------------------------------------
// Flash attention, K-split=2, no running max.  (r10 configuration — best
// measured total 164.0 us.  K-split=4 arc refuted twice: r11 spilled at
// (512,8); r12's finer split cost uncoalesced 2-byte partial stores
// (+7 MB WRITE), doubled bank conflicts, and COLLAPSED time-averaged
// occupancy to 29% because quarter-splits destroy the uniform-17-iter
// block property.  This version: 8 waves x 16 q-rows, grid 512, uniform
// pieces {qp,15-qp}, counted-vmcnt two-barrier pipeline, 64 VGPR.)
// ---------------------------------------------------------------------------
__global__ __launch_bounds__(512, 4) void attn_bf16(
    const ushort* __restrict__ Qh, const ushort* __restrict__ Kh,
    const ushort* __restrict__ VT, ushort* __restrict__ Opart, float* __restrict__ Lp)
{
    __shared__ __align__(16) ushort Ks[2][64 * 64];   // [krow][d^swz]
    __shared__ __align__(16) ushort Vt[2][64 * 64];   // [d][k^swz]

    const int x = blockIdx.x;            // 512 blocks
    const int bh = x & 31;               // same-bh blocks share an XCD (x%8==bh%8)
    const int y = x >> 5;                // [0,16)
    const int s = y & 1;
    const int qp = y >> 1;               // [0,8)

    const int tid = threadIdx.x;
    const int w = tid >> 6, lane = tid & 63;   // w in [0,8)
    const int lq = lane & 15, quad = lane >> 4;
    const int kswz = (lq & 7) << 3;

    const ushort* kbase = Kh + (size_t)bh * 2048 * 64;
    const ushort* vbase = VT + (size_t)bh * 64 * 2048;
    // staging: 512 thr x 16B = 8 KB = one full 64x64 bf16 tile per issue
    const int kr = tid >> 3, ko = (tid & 7) * 8;      // kr in [0,64)

    auto stage = [&](int kt, int bufi) {
        gl_lds16(kbase + (size_t)kt * 64 * 64 + kr * 64 + ko, &Ks[bufi][tid * 8]);
        gl_lds16(vbase + (size_t)kr * 2048 + kt * 64 + ko,    &Vt[bufi][tid * 8]);
    };

    const s4v ones = { (short)0x3F80, (short)0x3F80, (short)0x3F80, (short)0x3F80 };

#pragma unroll 1
    for (int piece = 0; piece < 2; ++piece) {
        const int qt = piece ? (15 - qp) : qp;
        const int qrow_base = qt * 128 + w * 16;      // 8 waves x 16 rows
        const int diag = 2 * qt + (w >> 2);           // wave's K-tile on the diagonal
        const int kt_lo = s ? (qt + 1) : 0;
        const int niter = qt + 1;                     // both splits: qt+1 K-tiles

        // piece 2: ensure all waves finished piece-1 reads before buf0 reuse
        if (piece) __builtin_amdgcn_s_barrier();

        s8v qf[2];
#pragma unroll
        for (int sb = 0; sb < 2; ++sb)
            qf[sb] = *(const s8v*)(Qh + ((size_t)bh * 2048 + qrow_base + lq) * 64
                                   + sb * 32 + quad * 8);

        f4v o[4];
#pragma unroll
        for (int dg = 0; dg < 4; ++dg) o[dg] = 0.f;
        f4v lacc = 0.f;

        auto compute = [&](int ktc, int bufi) {
            if (ktc > diag) return;
            f4v st[4];
#pragma unroll
            for (int kg = 0; kg < 4; ++kg) st[kg] = 0.f;
#pragma unroll
            for (int kg = 0; kg < 4; ++kg)
#pragma unroll
                for (int sb = 0; sb < 2; ++sb) {
                    const s8v af = *(const s8v*)&Ks[bufi][(kg * 16 + lq) * 64
                                                         + ((sb * 32 + quad * 8) ^ kswz)];
                    st[kg] = MFMA_16x16x32(af, qf[sb], st[kg]);
                }
            if (ktc == diag) {
                const int qrow = qrow_base + lq;
#pragma unroll
                for (int kg = 0; kg < 4; ++kg)
#pragma unroll
                    for (int r = 0; r < 4; ++r)
                        if (ktc * 64 + kg * 16 + quad * 4 + r > qrow)
                            st[kg][r] = -INFINITY;
            }
#pragma unroll
            for (int kg = 0; kg < 4; ++kg)
#pragma unroll
                for (int r = 0; r < 4; ++r)
                    st[kg][r] = exp2f(st[kg][r]);
#pragma unroll
            for (int ks = 0; ks < 4; ++ks) {
                s4v pb;
                {
                    union { s4v v; uint2 u; } c;
                    c.u.x = pkrnd(st[ks][0], st[ks][1]);
                    c.u.y = pkrnd(st[ks][2], st[ks][3]);
                    pb = c.v;
                }
                lacc = MFMA_16x16x16(ones, pb, lacc);
#pragma unroll
                for (int dg = 0; dg < 4; ++dg) {
                    const s4v va = *(const s4v*)&Vt[bufi][(dg * 16 + lq) * 64
                                                         + ((ks * 16 + quad * 4) ^ kswz)];
                    o[dg] = MFMA_16x16x16(va, pb, o[dg]);
                }
            }
        };

        stage(kt_lo, 0);                           // 2 loads in flight
#pragma unroll 1
        for (int i = 0; i < niter; ++i) {
            const int cur = i & 1;
            __builtin_amdgcn_s_barrier();          // B1: all compute(i-1) done
            if (i + 1 < niter) {
                stage(kt_lo + i + 1, cur ^ 1);     // +2 -> 4 outstanding
                asm volatile("s_waitcnt vmcnt(2)" ::: "memory");   // retire buf-i's 2
            } else {
                asm volatile("s_waitcnt vmcnt(0)" ::: "memory");   // piece tail drain
            }
            __builtin_amdgcn_s_barrier();          // B2: everyone's buf-i landed
            compute(kt_lo + i, cur);
        }

        // piece epilogue: wave writes its 16 rows
        {
            const size_t prow = (size_t)(s * 32 + bh) * 2048 + qrow_base + lq;
#pragma unroll
            for (int dg = 0; dg < 4; ++dg) {
                const int d = dg * 16 + quad * 4;
                uint2 u;
                u.x = bfpk(o[dg][0], o[dg][1]);
                u.y = bfpk(o[dg][2], o[dg][3]);
                *(uint2*)&Opart[prow * 64 + d] = u;
            }
            if (quad == 0) Lp[prow] = lacc[0];
        }
    }
}

// ---------------------------------------------------------------------------
// Combine the two K-split partials -> final f32 output [B, L, D].
// ---------------------------------------------------------------------------
__global__ __launch_bounds__(256) void attn_combine(
    const ushort* __restrict__ Opart, const float* __restrict__ Lp, float* __restrict__ Out)
{
    const int id = blockIdx.x * 256 + threadIdx.x;
    const int row = id >> 4, c4 = (id & 15) * 4;
    const float l0 = Lp[row], l1 = Lp[row + NROWS];
    const float inv = 1.0f / (l0 + l1);

    const s4v a = *(const s4v*)&Opart[(size_t)row * 64 + c4];
    const s4v c = *(const s4v*)&Opart[(size_t)(row + NROWS) * 64 + c4];
    float4 v;
    v.x = (bf2f((unsigned short)a[0]) + bf2f((unsigned short)c[0])) * inv;
    v.y = (bf2f((unsigned short)a[1]) + bf2f((unsigned short)c[1])) * inv;
    v.z = (bf2f((unsigned short)a[2]) + bf2f((unsigned short)c[2])) * inv;
    v.w = (bf2f((unsigned short)a[3]) + bf2f((unsigned short)c[3])) * inv;

    const int bh = row >> 11, qrow = row & 2047;
    const int b = bh >> 4, h = bh & 15;
    *(float4*)(Out + ((size_t)(b * 2048 + qrow)) * 1024 + h * 64 + c4) = v;
}

// ---------------------------------------------------------------------------
extern "C" void kernel_launch(void* const* d_in, const int* in_sizes, int n_in,
                              void* d_out, int out_size, void* d_ws, size_t ws_size,
                              hipStream_t stream)
{
    const float* x  = (const float*)d_in[0];  // [2,2048,1024] f32
    const float* wq = (const float*)d_in[1];  // [1024,3072] f32
    float* out = (float*)d_out;               // [2,2048,1024] f32

    const size_t HEADTEN = (size_t)32 * 2048 * 64;   // 8.4 MB bf16 each
    ushort* wsp = (ushort*)d_ws;
    ushort* qh = wsp;
    ushort* kh = qh + HEADTEN;
    ushort* vt = kh + HEADTEN;
    ushort* xb = vt + HEADTEN;           // dead after GEMM
    ushort* wt = xb + (size_t)GM * GK;   // dead after GEMM
    ushort* opart = xb;                                        // overlays xb/wt
    float*  lp    = (float*)(opart + (size_t)2 * NROWS * 64);

    conv_fused<<<2816, 256, 0, stream>>>(x, wq, xb, wt);
    qkv_gemm_bf16<<<256, 512, 0, stream>>>(xb, wt, qh, kh, vt);
    attn_bf16<<<512, 512, 0, stream>>>(qh, kh, vt, opart, lp);
    attn_combine<<<NROWS * 16 / 256, 256, 0, stream>>>(opart, lp, out);
}